// Round 5
// baseline (290.430 us; speedup 1.0000x reference)
//
#include <hip/hip_runtime.h>
#include <math.h>

// Problem constants
#define B_   2
#define T_   2048
#define D_   1024
#define C_   10
#define F_   513
#define NTOK (B_ * T_)     // 4096 rows
#define LF   3078          // Fall stride = 6*F_ : [qR qI kR kI vR vI]
#define KP2  1056          // padded K for output GEMM (mult of 32)
#define OIM2 528           // Im block offset inside Rcat/MoutT (16-elem aligned)
#define NCH  128           // scan chunks
#define TC   (T_ / NCH)    // 16 timesteps per chunk

typedef unsigned short us16;
typedef __attribute__((ext_vector_type(8))) __bf16 bf16x8;
typedef __attribute__((ext_vector_type(4))) float  f32x4;

// Workspace layout (bytes)
#define O_XBF    ((size_t)0)                       // x bf16: 8,388,608
#define O_PREP   ((size_t)8388608)                 // WT(3x2MB)+Wo_bf(2MB)+Tcs = 10,489,856
#define O_WT     (O_PREP)
#define O_WOBF   (O_PREP + 6291456)
#define O_TCS    (O_PREP + 8388608)
#define O_RCAT   (O_PREP)                          // Rcat bf16 aliases PREP after builders
#define O_SFB    (O_PREP + 10489856)               // S trig: 2,162,688
#define O_MALLB  (O_SFB + 2162688)                 // Mall bf16: 6,303,744
#define O_MOUTB  (O_MALLB + 6303744)               // MoutT bf16: 2,162,688
#define O_FALL   (O_MOUTB + 2162688)               // Fall fp32: 50,429,952
#define O_SSCAN  (O_FALL + 50429952)               // scan sums fp32: 10,506,240

__device__ __forceinline__ us16 f2b(float f) {
    union { float f; unsigned u; } v; v.f = f;
    unsigned r = v.u + 0x7FFFu + ((v.u >> 16) & 1u);
    return (us16)(r >> 16);
}

// ---------------------------------------------------------------------------
// float -> bf16 copy-convert (vectorized by 4)
// ---------------------------------------------------------------------------
__global__ void hrr_cvt_bf16(const float* __restrict__ in, us16* __restrict__ out, int n4) {
    int i = blockIdx.x * 256 + threadIdx.x;
    if (i < n4) {
        float4 v = ((const float4*)in)[i];
        ushort4 o;
        o.x = f2b(v.x); o.y = f2b(v.y); o.z = f2b(v.z); o.w = f2b(v.w);
        ((ushort4*)out)[i] = o;
    }
}

// ---------------------------------------------------------------------------
// Transpose W (1024x1024 fp32) -> bf16, 3 matrices via blockIdx.z
// ---------------------------------------------------------------------------
__global__ void hrr_transpose_bf16(const float* __restrict__ Wq,
                                   const float* __restrict__ Wk,
                                   const float* __restrict__ Wv,
                                   us16* __restrict__ WT) {
    const float* W = (blockIdx.z == 0) ? Wq : (blockIdx.z == 1) ? Wk : Wv;
    us16* O = WT + (size_t)blockIdx.z * D_ * D_;
    __shared__ float t[32][33];
    const int bx = blockIdx.x * 32, by = blockIdx.y * 32;
    const int tx = threadIdx.x & 31, ty = threadIdx.x >> 5;   // 32 x 8
#pragma unroll
    for (int i = 0; i < 32; i += 8)
        t[ty + i][tx] = W[(size_t)(by + ty + i) * D_ + bx + tx];
    __syncthreads();
#pragma unroll
    for (int i = 0; i < 32; i += 8)
        O[(size_t)(bx + ty + i) * D_ + by + tx] = f2b(t[tx][ty + i]);
}

// ---------------------------------------------------------------------------
// Tcs (1026 x 1024 bf16): rows 0..512 = cos(2*pi*f*e/1024); rows 513.. = -sin
// ---------------------------------------------------------------------------
__global__ void hrr_build_tcs(us16* __restrict__ Tcs) {
    int idx = blockIdx.x * 256 + threadIdx.x;
    if (idx >= 1026 * 1024) return;
    int r = idx >> 10, e = idx & 1023;
    int f = (r < F_) ? r : r - F_;
    int m = (f * e) & 1023;
    float ang = (float)m * 6.135923151542565e-3f;   // 2*pi/1024
    float v = (r < F_) ? cosf(ang) : -sinf(ang);
    Tcs[idx] = f2b(v);
}

// ---------------------------------------------------------------------------
// S (1056 x 1024 bf16): rows 0..512 = scale_f*cos ; rows 528..1040 = -scale_f*sin
// ---------------------------------------------------------------------------
__global__ void hrr_build_sfb(us16* __restrict__ S) {
    int idx = blockIdx.x * 256 + threadIdx.x;
    if (idx >= KP2 * 1024) return;
    int r = idx >> 10, e = idx & 1023;
    float v = 0.f;
    if (r < F_) {
        float scale = (r == 0 || r == 512) ? (1.0f / 1024.0f) : (2.0f / 1024.0f);
        v = scale * cosf((float)((r * e) & 1023) * 6.135923151542565e-3f);
    } else if (r >= OIM2 && r < OIM2 + F_) {
        int f = r - OIM2;
        float scale = (f == 0 || f == 512) ? (1.0f / 1024.0f) : (2.0f / 1024.0f);
        v = -scale * sinf((float)((f * e) & 1023) * 6.135923151542565e-3f);
    }
    S[idx] = f2b(v);
}

// ---------------------------------------------------------------------------
// bf16 MFMA GEMM, register-double-buffered: C(MxN) = A(MxK) @ B(NxK)^T.
// 128x128 tile, 256 threads (2x2 waves of 64x64), K-step 32, 16x16x32 MFMA.
// Tile k+1 is loaded into VGPRs BEFORE the MFMAs of tile k, so the ~400-cycle
// global-load latency hides behind compute instead of the barrier drain.
// K mult 32, lda/ldb mult 8. M/N edges: staging rows clamp, epilogue guards.
// ---------------------------------------------------------------------------
template <bool OUT_BF16>
__global__ __launch_bounds__(256, 3)
void hrr_gemm_mfma(const us16* __restrict__ Ab, const us16* __restrict__ Bb,
                   void* __restrict__ Cv, int M, int N, int K,
                   int lda, int ldb, int ldc,
                   size_t strideA, size_t strideB, size_t strideC) {
    const us16* A = Ab + strideA * blockIdx.z;
    const us16* B = Bb + strideB * blockIdx.z;

    __shared__ us16 As[128 * 32];
    __shared__ us16 Bs[128 * 32];

    const int tid  = threadIdx.x;
    const int lane = tid & 63;
    const int wave = tid >> 6;
    const int wm = (wave >> 1) * 64;
    const int wn = (wave & 1) * 64;
    const int bm = blockIdx.y * 128;
    const int bn = blockIdx.x * 128;

    const int r0 = tid >> 2;          // 0..63 staging row
    const int c4 = (tid & 3) * 8;     // k-offset in elements (16B granules)

    int rA0 = bm + r0;      if (rA0 >= M) rA0 = M - 1;
    int rA1 = bm + 64 + r0; if (rA1 >= M) rA1 = M - 1;
    int rB0 = bn + r0;      if (rB0 >= N) rB0 = N - 1;
    int rB1 = bn + 64 + r0; if (rB1 >= N) rB1 = N - 1;
    const us16* pA0 = A + (size_t)rA0 * lda + c4;
    const us16* pA1 = A + (size_t)rA1 * lda + c4;
    const us16* pB0 = B + (size_t)rB0 * ldb + c4;
    const us16* pB1 = B + (size_t)rB1 * ldb + c4;

    f32x4 acc[4][4];
#pragma unroll
    for (int i = 0; i < 4; i++)
#pragma unroll
        for (int j = 0; j < 4; j++) acc[i][j] = (f32x4){0.f, 0.f, 0.f, 0.f};

    const int fr = lane & 15;
    const int kg = (lane >> 4) * 8;

    // prologue: tile 0 into registers
    uint4 a0 = *(const uint4*)(pA0);
    uint4 a1 = *(const uint4*)(pA1);
    uint4 b0 = *(const uint4*)(pB0);
    uint4 b1 = *(const uint4*)(pB1);

    for (int k0 = 0; k0 < K; k0 += 32) {
        __syncthreads();                            // prior readers done
        *(uint4*)(As + r0 * 32 + c4)        = a0;
        *(uint4*)(As + (64 + r0) * 32 + c4) = a1;
        *(uint4*)(Bs + r0 * 32 + c4)        = b0;
        *(uint4*)(Bs + (64 + r0) * 32 + c4) = b1;
        __syncthreads();

        const int kn = k0 + 32;
        if (kn < K) {                               // prefetch next tile (no wait)
            a0 = *(const uint4*)(pA0 + kn);
            a1 = *(const uint4*)(pA1 + kn);
            b0 = *(const uint4*)(pB0 + kn);
            b1 = *(const uint4*)(pB1 + kn);
        }

        bf16x8 af[4], bfr[4];
#pragma unroll
        for (int i = 0; i < 4; i++)
            af[i] = *(const bf16x8*)(As + (wm + i * 16 + fr) * 32 + kg);
#pragma unroll
        for (int j = 0; j < 4; j++)
            bfr[j] = *(const bf16x8*)(Bs + (wn + j * 16 + fr) * 32 + kg);
#pragma unroll
        for (int i = 0; i < 4; i++)
#pragma unroll
            for (int j = 0; j < 4; j++)
                acc[i][j] = __builtin_amdgcn_mfma_f32_16x16x32_bf16(af[i], bfr[j], acc[i][j], 0, 0, 0);
    }

    // epilogue: C/D layout col=lane&15, row=(lane>>4)*4+reg
    const int cl = lane & 15;
    const int rq = (lane >> 4) * 4;
#pragma unroll
    for (int i = 0; i < 4; i++) {
#pragma unroll
        for (int j = 0; j < 4; j++) {
#pragma unroll
            for (int r = 0; r < 4; r++) {
                int row = bm + wm + i * 16 + rq + r;
                int col = bn + wn + j * 16 + cl;
                if (row < M && col < N) {
                    size_t o = strideC * blockIdx.z + (size_t)row * ldc + col;
                    if (OUT_BF16) ((us16*)Cv)[o] = f2b(acc[i][j][r]);
                    else          ((float*)Cv)[o] = acc[i][j][r];
                }
            }
        }
    }
}

// ---------------------------------------------------------------------------
// Scan phase 1: chunk sums. Grid (NCH, B_, 2): z halves the f-range for 2x
// block-level latency hiding. 256 threads: z=0 owns f=tid (0..255);
// z=1 owns f=256+tid (256..511) plus f=512 on thread 0.
// k staged full-range (perm gathers span all bins); v staged half-range.
// ---------------------------------------------------------------------------
__global__ __launch_bounds__(256, 4)
void hrr_scan_sums(const float* __restrict__ Fall, const int* __restrict__ perms,
                   float* __restrict__ S) {
    const int n = blockIdx.x, b = blockIdx.y, half = blockIdx.z;
    const int tid = threadIdx.x;
    const int f0 = half * 256;
    const int VL = half ? 257 : 256;               // local v length
    __shared__ float kR[F_], kI[F_], vR[257], vI[257];

    float aR[2][C_], aI[2][C_];
    int gg[2][C_];
#pragma unroll
    for (int i = 0; i < 2; i++) {
        const int f = (i == 0) ? (f0 + tid) : 512;
        const bool act = (i == 0) || (half == 1 && tid == 0);
#pragma unroll
        for (int c = 0; c < C_; c++) {
            gg[i][c] = act ? perms[c * F_ + f] : 0;
            aR[i][c] = aI[i][c] = 0.f;
        }
    }

    for (int tl = 0; tl < TC; tl++) {
        const int tt = b * T_ + n * TC + tl;
        const float* row = Fall + (size_t)tt * LF;
        __syncthreads();
        for (int j = tid; j < F_; j += 256) {
            kR[j] = row[2 * F_ + j]; kI[j] = row[3 * F_ + j];
        }
        for (int j = tid; j < VL; j += 256) {
            vR[j] = row[4 * F_ + f0 + j]; vI[j] = row[5 * F_ + f0 + j];
        }
        __syncthreads();
#pragma unroll
        for (int i = 0; i < 2; i++) {
            const int lv = (i == 0) ? tid : 256;   // local v index
            if (i == 0 || (half == 1 && tid == 0)) {
                float br = vR[lv], bi = vI[lv];
#pragma unroll
                for (int c = 0; c < C_; c++) {
                    float ar = kR[gg[i][c]], ai = kI[gg[i][c]];
                    aR[i][c] += ar * br - ai * bi;
                    aI[i][c] += ar * bi + ai * br;
                }
            }
        }
    }
#pragma unroll
    for (int i = 0; i < 2; i++) {
        const int f = (i == 0) ? (f0 + tid) : 512;
        if (i == 0 || (half == 1 && tid == 0)) {
#pragma unroll
            for (int c = 0; c < C_; c++) {
                size_t a = ((((size_t)c * B_ + b) * NCH + n) * F_ + f) * 2;
                S[a] = aR[i][c]; S[a + 1] = aI[i][c];
            }
        }
    }
}

// ---------------------------------------------------------------------------
// Scan phase 2: exclusive prefix over chunks, per (c,b,f). 8-way unrolled.
// ---------------------------------------------------------------------------
__global__ void hrr_scan_prefix(float* __restrict__ S) {
    int tid = blockIdx.x * 256 + threadIdx.x;
    if (tid >= C_ * B_ * F_) return;
    int c = tid / (B_ * F_);
    int r = tid % (B_ * F_);
    int b = r / F_, f = r % F_;
    size_t base = (((size_t)c * B_ + b) * NCH) * F_ + f;
    float runR = 0.f, runI = 0.f;
    for (int n0 = 0; n0 < NCH; n0 += 8) {
        float tR[8], tI[8];
#pragma unroll
        for (int u = 0; u < 8; u++) {
            size_t a = (base + (size_t)(n0 + u) * F_) * 2;
            tR[u] = S[a]; tI[u] = S[a + 1];
        }
#pragma unroll
        for (int u = 0; u < 8; u++) {
            size_t a = (base + (size_t)(n0 + u) * F_) * 2;
            S[a] = runR; S[a + 1] = runI;
            runR += tR[u]; runI += tI[u];
        }
    }
}

// ---------------------------------------------------------------------------
// Scan phase 3: running kv in regs, r = mean_c kv*conj(fqp) -> Rcat (bf16).
// Grid (NCH, B_, 2) f-halves like phase 1; q/k staged full, v staged half.
// half==0 blocks also zero the 30 pad columns (replaces the Rcat memset).
// ---------------------------------------------------------------------------
__global__ __launch_bounds__(256, 4)
void hrr_scan_apply(const float* __restrict__ Fall, const int* __restrict__ perms,
                    const float* __restrict__ S, us16* __restrict__ Rcat) {
    const int n = blockIdx.x, b = blockIdx.y, half = blockIdx.z;
    const int tid = threadIdx.x;
    const int f0 = half * 256;
    const int VL = half ? 257 : 256;
    __shared__ float qR[F_], qI[F_], kR[F_], kI[F_], vR[257], vI[257];

    float kvR[2][C_], kvI[2][C_];
    int gg[2][C_];
#pragma unroll
    for (int i = 0; i < 2; i++) {
        const int f = (i == 0) ? (f0 + tid) : 512;
        const bool act = (i == 0) || (half == 1 && tid == 0);
#pragma unroll
        for (int c = 0; c < C_; c++) {
            gg[i][c] = act ? perms[c * F_ + f] : 0;
            if (act) {
                size_t a = ((((size_t)c * B_ + b) * NCH + n) * F_ + f) * 2;
                kvR[i][c] = S[a]; kvI[i][c] = S[a + 1];
            } else { kvR[i][c] = 0.f; kvI[i][c] = 0.f; }
        }
    }

    for (int tl = 0; tl < TC; tl++) {
        const int tt = b * T_ + n * TC + tl;
        const float* row = Fall + (size_t)tt * LF;
        __syncthreads();
        for (int j = tid; j < F_; j += 256) {
            qR[j] = row[j];           qI[j] = row[F_ + j];
            kR[j] = row[2 * F_ + j];  kI[j] = row[3 * F_ + j];
        }
        for (int j = tid; j < VL; j += 256) {
            vR[j] = row[4 * F_ + f0 + j]; vI[j] = row[5 * F_ + f0 + j];
        }
        __syncthreads();
        us16* out = Rcat + (size_t)tt * KP2;
#pragma unroll
        for (int i = 0; i < 2; i++) {
            const int f = (i == 0) ? (f0 + tid) : 512;
            const int lv = (i == 0) ? tid : 256;
            if (i == 0 || (half == 1 && tid == 0)) {
                float vr = vR[lv], vi = vI[lv];
                float accR = 0.f, accI = 0.f;
#pragma unroll
                for (int c = 0; c < C_; c++) {
                    int g = gg[i][c];
                    float ar = kR[g], ai = kI[g];
                    float nR = kvR[i][c] + ar * vr - ai * vi;
                    float nI = kvI[i][c] + ar * vi + ai * vr;
                    kvR[i][c] = nR; kvI[i][c] = nI;
                    float qr = qR[g], qi = qI[g];
                    accR += nR * qr + nI * qi;
                    accI += nI * qr - nR * qi;
                }
                out[f]        = f2b(accR * 0.1f);   // 1/C
                out[OIM2 + f] = f2b(accI * 0.1f);
            }
        }
        if (half == 0 && tid < 15) {                // zero pad columns
            out[F_ + tid] = 0;                      // 513..527
            out[OIM2 + F_ + tid] = 0;               // 1041..1055
        }
    }
}

// ---------------------------------------------------------------------------
extern "C" void kernel_launch(void* const* d_in, const int* in_sizes, int n_in,
                              void* d_out, int out_size, void* d_ws, size_t ws_size,
                              hipStream_t stream) {
    const float* x  = (const float*)d_in[0];
    const float* Wq = (const float*)d_in[1];
    const float* Wk = (const float*)d_in[2];
    const float* Wv = (const float*)d_in[3];
    const float* Wo = (const float*)d_in[4];
    const int* perms = (const int*)d_in[5];
    float* out = (float*)d_out;

    char* ws = (char*)d_ws;
    us16* Xbf   = (us16*)(ws + O_XBF);
    us16* WT    = (us16*)(ws + O_WT);
    us16* WoBf  = (us16*)(ws + O_WOBF);
    us16* Tcs   = (us16*)(ws + O_TCS);
    us16* Sfb   = (us16*)(ws + O_SFB);
    us16* MallB = (us16*)(ws + O_MALLB);
    us16* MoutB = (us16*)(ws + O_MOUTB);
    us16* Rcat  = (us16*)(ws + O_RCAT);
    float* Fall = (float*)(ws + O_FALL);
    float* Ssc  = (float*)(ws + O_SSCAN);

    // prep: converts / transposes / trig matrices
    hrr_cvt_bf16<<<4096, 256, 0, stream>>>(x, Xbf, NTOK * D_ / 4);
    hrr_cvt_bf16<<<1024, 256, 0, stream>>>(Wo, WoBf, D_ * D_ / 4);
    hrr_transpose_bf16<<<dim3(32, 32, 3), 256, 0, stream>>>(Wq, Wk, Wv, WT);
    hrr_build_tcs<<<(1026 * 1024 + 255) / 256, 256, 0, stream>>>(Tcs);
    hrr_build_sfb<<<(KP2 * 1024 + 255) / 256, 256, 0, stream>>>(Sfb);

    // builder 1: Mall_w(1026x1024) = Tcs @ WT_w^T, bf16 out, batched over w
    hrr_gemm_mfma<true><<<dim3(8, 9, 3), 256, 0, stream>>>(
        Tcs, WT, MallB, 1026, 1024, 1024, 1024, 1024, 1024,
        0, (size_t)D_ * D_, (size_t)1026 * 1024);

    // builder 2: MoutT(1024x1056) = Wo @ S^T, bf16 out
    hrr_gemm_mfma<true><<<dim3(9, 8, 1), 256, 0, stream>>>(
        WoBf, Sfb, MoutB, 1024, KP2, 1024, 1024, 1024, KP2, 0, 0, 0);

    // main GEMM: Fall(4096x3078) = Xbf @ MallB^T, fp32 out
    hrr_gemm_mfma<false><<<dim3(25, 32, 1), 256, 0, stream>>>(
        Xbf, MallB, Fall, NTOK, LF, 1024, 1024, 1024, LF, 0, 0, 0);

    // chunked causal scan (scan_apply zeroes Rcat pad columns itself)
    hrr_scan_sums<<<dim3(NCH, B_, 2), 256, 0, stream>>>(Fall, perms, Ssc);
    hrr_scan_prefix<<<(C_ * B_ * F_ + 255) / 256, 256, 0, stream>>>(Ssc);
    hrr_scan_apply<<<dim3(NCH, B_, 2), 256, 0, stream>>>(Fall, perms, Ssc, Rcat);

    // output GEMM: out(4096x1024) = Rcat(4096x1056) @ MoutB(1024x1056)^T, fp32
    hrr_gemm_mfma<false><<<dim3(8, 32, 1), 256, 0, stream>>>(
        Rcat, MoutB, out, NTOK, D_, KP2, KP2, KP2, D_, 0, 0, 0);
}